// Round 1
// baseline (271.454 us; speedup 1.0000x reference)
//
#include <hip/hip_runtime.h>
#include <hip/hip_bf16.h>
#include <math.h>

#define NROWS 8192
#define DDIM  4096
#define NEXP  64
#define BN    64
#define BK    64
#define KSPLIT 2
#define KHALF (DDIM/KSPLIT)   // 2048
#define NITER (KHALF/BK)      // 32

// Stage 1: partial logits, split-K by 2. part[kh][row][e], fp32.
// Block tile: 64 rows x 64 experts, BK=64. 256 threads, per-thread 4x4.
__global__ __launch_bounds__(256) void gemm_partial_kernel(
    const float* __restrict__ x, const float* __restrict__ w,
    float* __restrict__ part)
{
    // xs: [row][k] stride 68 (16B-aligned rows, avoids pow2 bank stride)
    // wt: [k][e]  stride 68 (transposed on the fly during staging)
    __shared__ float xs[BN][BK + 4];
    __shared__ float wt[BK][NEXP + 4];

    const int tid = threadIdx.x;
    const int tx  = tid & 15;   // expert group: experts 4*tx..4*tx+3
    const int ty  = tid >> 4;   // row group: rows ty+16*i
    const int r0  = blockIdx.x * BN;
    const int kh  = blockIdx.y;

    // staging assignment: 16 floats (4 x float4) per thread
    const int lrow = tid >> 2;          // 0..63
    const int lcol = (tid & 3) << 4;    // 0,16,32,48

    const float* xp = x + (size_t)(r0 + lrow) * DDIM + (size_t)kh * KHALF + lcol;
    const float* wp = w + (size_t)lrow * DDIM + (size_t)kh * KHALF + lcol;

    float acc[4][4];
#pragma unroll
    for (int i = 0; i < 4; i++)
#pragma unroll
        for (int j = 0; j < 4; j++) acc[i][j] = 0.f;

    // register prefetch of tile 0
    float4 xa[4], wa[4];
#pragma unroll
    for (int u = 0; u < 4; u++) {
        xa[u] = *(const float4*)(xp + 4 * u);
        wa[u] = *(const float4*)(wp + 4 * u);
    }

    for (int kt = 0; kt < NITER; ++kt) {
        // write prefetched tile into LDS (x direct, W transposed scatter)
#pragma unroll
        for (int u = 0; u < 4; u++) {
            *(float4*)&xs[lrow][lcol + 4 * u] = xa[u];
            wt[lcol + 4 * u + 0][lrow] = wa[u].x;
            wt[lcol + 4 * u + 1][lrow] = wa[u].y;
            wt[lcol + 4 * u + 2][lrow] = wa[u].z;
            wt[lcol + 4 * u + 3][lrow] = wa[u].w;
        }
        __syncthreads();

        // issue next tile's global loads; latency hidden behind compute
        if (kt + 1 < NITER) {
            const float* xpn = xp + (size_t)(kt + 1) * BK;
            const float* wpn = wp + (size_t)(kt + 1) * BK;
#pragma unroll
            for (int u = 0; u < 4; u++) {
                xa[u] = *(const float4*)(xpn + 4 * u);
                wa[u] = *(const float4*)(wpn + 4 * u);
            }
        }

        // compute: per 4k group: 4+4 ds_read_b128, 64 FMAs
#pragma unroll
        for (int kk = 0; kk < BK; kk += 4) {
            float4 a[4], b[4];
#pragma unroll
            for (int i = 0; i < 4; i++) a[i] = *(const float4*)&xs[ty + 16 * i][kk];
#pragma unroll
            for (int j = 0; j < 4; j++) b[j] = *(const float4*)&wt[kk + j][tx * 4];
#pragma unroll
            for (int i = 0; i < 4; i++) {
                const float* af = (const float*)&a[i];
#pragma unroll
                for (int k2 = 0; k2 < 4; k2++) {
                    const float* bf = (const float*)&b[k2];
                    const float av = af[k2];
                    acc[i][0] += av * bf[0];
                    acc[i][1] += av * bf[1];
                    acc[i][2] += av * bf[2];
                    acc[i][3] += av * bf[3];
                }
            }
        }
        __syncthreads();
    }

    float* po = part + (size_t)kh * NROWS * NEXP;
#pragma unroll
    for (int i = 0; i < 4; i++) {
        float4 v = make_float4(acc[i][0], acc[i][1], acc[i][2], acc[i][3]);
        *(float4*)&po[(size_t)(r0 + ty + 16 * i) * NEXP + tx * 4] = v;
    }
}

// Stage 2: one wave per row (lane = expert). Sum K-halves, sigmoid, +bias,
// top-2 via butterfly argmax (tie -> lower index), normalize, write outputs.
// out layout: [weights 2*N][indices-as-float 2*N][scores 64*N]
__global__ __launch_bounds__(256) void gate_topk_kernel(
    const float* __restrict__ part, const float* __restrict__ bias,
    float* __restrict__ out)
{
    const int tid = threadIdx.x;
    const int e   = tid & 63;
    const int row = blockIdx.x * 4 + (tid >> 6);
    const size_t idx = (size_t)row * NEXP + e;

    const float logit = part[idx] + part[(size_t)NROWS * NEXP + idx];
    const float score = 1.0f / (1.0f + expf(-logit));
    out[(size_t)4 * NROWS + idx] = score;           // scores

    const float biased = score + bias[e];

    float v = biased; int bi = e;
#pragma unroll
    for (int off = 32; off; off >>= 1) {
        const float ov = __shfl_xor(v, off);
        const int   oi = __shfl_xor(bi, off);
        if (ov > v || (ov == v && oi < bi)) { v = ov; bi = oi; }
    }
    const int i1 = bi;

    float v2 = (e == i1) ? -INFINITY : biased;
    int bi2 = e;
#pragma unroll
    for (int off = 32; off; off >>= 1) {
        const float ov = __shfl_xor(v2, off);
        const int   oi = __shfl_xor(bi2, off);
        if (ov > v2 || (ov == v2 && oi < bi2)) { v2 = ov; bi2 = oi; }
    }
    const int i2 = bi2;

    const float s1 = __shfl(score, i1);
    const float s2 = __shfl(score, i2);
    if (e == 0) {
        const float inv = 1.0f / (s1 + s2);
        out[(size_t)row * 2 + 0] = s1 * inv;        // weights
        out[(size_t)row * 2 + 1] = s2 * inv;
        out[(size_t)2 * NROWS + row * 2 + 0] = (float)i1;  // indices (as float)
        out[(size_t)2 * NROWS + row * 2 + 1] = (float)i2;
    }
}

extern "C" void kernel_launch(void* const* d_in, const int* in_sizes, int n_in,
                              void* d_out, int out_size, void* d_ws, size_t ws_size,
                              hipStream_t stream)
{
    const float* x    = (const float*)d_in[0];
    const float* w    = (const float*)d_in[1];
    const float* bias = (const float*)d_in[2];
    float* out  = (float*)d_out;
    float* part = (float*)d_ws;   // 2 * 8192 * 64 fp32 = 4 MB

    dim3 g1(NROWS / BN, KSPLIT);
    gemm_partial_kernel<<<g1, 256, 0, stream>>>(x, w, part);
    gate_topk_kernel<<<NROWS / 4, 256, 0, stream>>>(part, bias, out);
}